// Round 1
// 661.268 us; speedup vs baseline: 1.0627x; 1.0627x over previous
//
#include <hip/hip_runtime.h>
#include <stdint.h>

// LSTM2Encoder: x=emb[ids]; h0=lstm0(x); h1=lstm1(h0); out=relu(h1@Wlin^T+b)
// R3: operand-swapped MFMA epilogue. mfma(b, a, acc) transposes C so rows =
// permuted-N (gate-inner: W'[4u+g]) -> each lane's 4 acc regs ARE gates
// i,f,g,o of one unit. Deletes the 96-shuffle 4x4 lane transpose + cndmask
// network per thread; bias becomes one float4 per j-tile. MODE 1 gets
// contiguous float4 stores. hT stride 34->36 (16B aligned) for ds_read_b128
// readback. prep vectorized 8 elem/thread.
// K-loop (staging swizzle, gl2lds, fragment reads) is unchanged from R2.

typedef _Float16 half8 __attribute__((ext_vector_type(8)));
typedef __attribute__((ext_vector_type(4))) float float4v;
typedef __attribute__((ext_vector_type(4))) unsigned int uint4v;

__device__ __forceinline__ float sigmoidf_(float x) { return 1.0f / (1.0f + __expf(-x)); }
__device__ __forceinline__ float tanhf_(float x) { return 1.0f - 2.0f / (__expf(2.0f * x) + 1.0f); }

__device__ __forceinline__ void gl2lds16(const void* g, void* l) {
  __builtin_amdgcn_global_load_lds(
      (const __attribute__((address_space(1))) void*)g,
      (__attribute__((address_space(3))) void*)l, 16, 0, 0);
}

// ---------------- prep: emb->fp16; weights permuted+cast; biases folded ----
// W'[4j+g][k] = W[g*512+j][k]  (g in {i,f,g,o});  b'[4j+g] = b_ih[n]+b_hh[n]
// Vectorized 8 elems/thread for all cast/permute regions (k is contiguous
// per permuted row, so 8-wide chunks stay coalesced on both sides).
__global__ __launch_bounds__(256) void prep_kernel(
    const float* __restrict__ emb,
    const float* __restrict__ W0, const float* __restrict__ bi0, const float* __restrict__ bh0,
    const float* __restrict__ W1, const float* __restrict__ bi1, const float* __restrict__ bh1,
    const float* __restrict__ WL,
    _Float16* __restrict__ Ef,
    _Float16* __restrict__ W0f, _Float16* __restrict__ W1f, _Float16* __restrict__ WLf,
    float* __restrict__ b0p, float* __restrict__ b1p)
{
  int id = blockIdx.x * 256 + threadIdx.x;
  if (id < 3216448) {                               // emb cast (50257*512/8)
    const float* s = emb + (size_t)id * 8;
    float4v v0 = *(const float4v*)s;
    float4v v1 = *(const float4v*)(s + 4);
    union { _Float16 h[8]; uint4v u; } P;
#pragma unroll
    for (int e = 0; e < 4; ++e) { P.h[e] = (_Float16)v0[e]; P.h[4 + e] = (_Float16)v1[e]; }
    *(uint4v*)(Ef + (size_t)id * 8) = P.u;
  } else if (id < 3347520) {                        // W0 permute+cast (2048*512/8)
    int u = id - 3216448;
    int np = u >> 6, k0 = (u & 63) << 3;
    int n = ((np & 3) << 9) | (np >> 2);
    const float* s = W0 + n * 512 + k0;
    float4v v0 = *(const float4v*)s;
    float4v v1 = *(const float4v*)(s + 4);
    union { _Float16 h[8]; uint4v u; } P;
#pragma unroll
    for (int e = 0; e < 4; ++e) { P.h[e] = (_Float16)v0[e]; P.h[4 + e] = (_Float16)v1[e]; }
    *(uint4v*)(W0f + np * 512 + k0) = P.u;
  } else if (id < 3478592) {                        // W1
    int u = id - 3347520;
    int np = u >> 6, k0 = (u & 63) << 3;
    int n = ((np & 3) << 9) | (np >> 2);
    const float* s = W1 + n * 512 + k0;
    float4v v0 = *(const float4v*)s;
    float4v v1 = *(const float4v*)(s + 4);
    union { _Float16 h[8]; uint4v u; } P;
#pragma unroll
    for (int e = 0; e < 4; ++e) { P.h[e] = (_Float16)v0[e]; P.h[4 + e] = (_Float16)v1[e]; }
    *(uint4v*)(W1f + np * 512 + k0) = P.u;
  } else if (id < 3511360) {                        // WL straight cast (512*512/8)
    int u = id - 3478592;
    const float* s = WL + (size_t)u * 8;
    float4v v0 = *(const float4v*)s;
    float4v v1 = *(const float4v*)(s + 4);
    union { _Float16 h[8]; uint4v u8; } P;
#pragma unroll
    for (int e = 0; e < 4; ++e) { P.h[e] = (_Float16)v0[e]; P.h[4 + e] = (_Float16)v1[e]; }
    *(uint4v*)(WLf + (size_t)u * 8) = P.u8;
  } else if (id < 3513408) {                        // b0 fold+permute
    int np = id - 3511360;
    int n = ((np & 3) << 9) | (np >> 2);
    b0p[np] = bi0[n] + bh0[n];
  } else if (id < 3515456) {                        // b1
    int np = id - 3513408;
    int n = ((np & 3) << 9) | (np >> 2);
    b1p[np] = bi1[n] + bh1[n];
  }
}

// ---------------- fused fp16 GEMM, 256x128 tile, BK=32 ---------------------
// Operand-swapped MFMA: acc[i][j] = mfma(b[j], a[i], acc) so
//   acc row  = permuted-N offset = 4*qf + reg  (reg = gate, qf = unit)
//   acc col  = token offset      = lane&15
// MODE 0: LSTM layer  -> h = sig(o)*tanh(sig(i)*tanh(g)), write h fp16
// MODE 1: final linear -> out = relu(acc + bias), float4 stores
template <int MODE>
__global__ __launch_bounds__(512, 4) void gemm_kernel(
    const _Float16* __restrict__ A, const int* __restrict__ ids,
    const _Float16* __restrict__ B, const float* __restrict__ bias,
    _Float16* __restrict__ Of, float* __restrict__ Out,
    int nbShift, int nbMask)
{
  __shared__ __align__(16) char smem[36864];        // K-loop 24KB; hT 36.9KB
  _Float16* sA = (_Float16*)smem;                   // 256 x 32
  _Float16* sB = (_Float16*)(smem + 16384);         // 128 x 32

  const int T = threadIdx.x;
  const int lane = T & 63;
  const int wv = T >> 6;
  const int wrow = wv >> 1, wcol = wv & 1;          // 4 x 2 wave grid
  const int mb = (int)blockIdx.x >> nbShift;
  const int nb = (int)blockIdx.x & nbMask;
  const size_t t0 = (size_t)mb * 256;
  const int n0 = nb * 128;

  // staging (R2-proven): thread T stages LDS chunk T (lane-contiguous 16B);
  // global k-quad XOR-swizzled by row so frag ds_read_b128 is 2-way (free).
  const int r0 = T >> 2;                            // 0..127
  const int qg = (T & 3) ^ ((r0 >> 1) & 3);
  size_t sr0 = t0 + r0, sr1 = t0 + 128 + r0;
  if (ids) { sr0 = (size_t)(unsigned)ids[sr0]; sr1 = (size_t)(unsigned)ids[sr1]; }
  const _Float16* gA0 = A + sr0 * 512 + qg * 8;
  const _Float16* gA1 = A + sr1 * 512 + qg * 8;
  const _Float16* gB  = B + (size_t)(n0 + r0) * 512 + qg * 8;

  // fragment read offsets (iter-invariant); un-swizzle with qs
  const int m_ = lane & 15, qf = lane >> 4;
  const int qs = qf ^ ((m_ >> 1) & 3);
  const int offA = wrow * 2048 + m_ * 32 + qs * 8;
  const int offB = wcol * 2048 + m_ * 32 + qs * 8;

  float4v acc[4][4];
#pragma unroll
  for (int i = 0; i < 4; ++i)
#pragma unroll
    for (int j = 0; j < 4; ++j)
      acc[i][j] = (float4v){0.f, 0.f, 0.f, 0.f};

  for (int it = 0; it < 16; ++it) {
    gl2lds16(gA0, sA + T * 8);                      // rows 0..127
    gl2lds16(gA1, sA + 4096 + T * 8);               // rows 128..255
    gl2lds16(gB,  sB + T * 8);
    gA0 += 32; gA1 += 32; gB += 32;
    __syncthreads();

    half8 a[4], b[4];
#pragma unroll
    for (int i = 0; i < 4; ++i) {
      a[i] = *(const half8*)(sA + offA + i * 512);
      b[i] = *(const half8*)(sB + offB + i * 512);
    }
#pragma unroll
    for (int i = 0; i < 4; ++i)
#pragma unroll
      for (int j = 0; j < 4; ++j)
        acc[i][j] = __builtin_amdgcn_mfma_f32_16x16x32_f16(b[j], a[i], acc[i][j], 0, 0, 0);
    __syncthreads();
  }

  // bias: acc rows are permuted-N -> 4 consecutive rows per lane = one float4
  float4v bq[4];
#pragma unroll
  for (int j = 0; j < 4; ++j)
    bq[j] = *(const float4v*)(bias + n0 + wcol * 64 + j * 16 + qf * 4);

  if (MODE == 0) {
    float* hT = (float*)smem;                       // 256 x 36 (16B-aligned rows)
#pragma unroll
    for (int i = 0; i < 4; ++i) {
      const int trow = wrow * 64 + i * 16 + m_;
#pragma unroll
      for (int j = 0; j < 4; ++j) {
        // regs = gates {i,f,g,o} of unit qf in j-tile; f never used (c_prev=0)
        float yi = acc[i][j][0] + bq[j][0];
        float yg = acc[i][j][2] + bq[j][2];
        float yo = acc[i][j][3] + bq[j][3];
        float cc = sigmoidf_(yi) * tanhf_(yg);
        float hh = sigmoidf_(yo) * tanhf_(cc);
        hT[trow * 36 + wcol * 16 + j * 4 + qf] = hh;
      }
    }
    __syncthreads();
    const int tl = T >> 1, hf = T & 1;
    const float* src = hT + tl * 36 + hf * 16;
    float4v r0 = *(const float4v*)(src);
    float4v r1 = *(const float4v*)(src + 4);
    float4v r2 = *(const float4v*)(src + 8);
    float4v r3 = *(const float4v*)(src + 12);
    union { _Float16 h[8]; uint4v v; } P0, P1;
#pragma unroll
    for (int e = 0; e < 4; ++e) {
      P0.h[e] = (_Float16)r0[e]; P0.h[4 + e] = (_Float16)r1[e];
      P1.h[e] = (_Float16)r2[e]; P1.h[4 + e] = (_Float16)r3[e];
    }
    _Float16* dst = Of + (t0 + tl) * 512 + (size_t)(nb * 32) + hf * 16;
    *(uint4v*)dst = P0.v;
    *(uint4v*)(dst + 8) = P1.v;
  } else {
#pragma unroll
    for (int i = 0; i < 4; ++i) {
      const size_t row = t0 + wrow * 64 + i * 16 + m_;
#pragma unroll
      for (int j = 0; j < 4; ++j) {
        float4v v;
#pragma unroll
        for (int r = 0; r < 4; ++r)
          v[r] = fmaxf(acc[i][j][r] + bq[j][r], 0.0f);
        *(float4v*)(Out + row * 512 + (size_t)(n0 + wcol * 64 + j * 16 + qf * 4)) = v;
      }
    }
  }
}

extern "C" void kernel_launch(void* const* d_in, const int* in_sizes, int n_in,
                              void* d_out, int out_size, void* d_ws, size_t ws_size,
                              hipStream_t stream) {
  (void)in_sizes; (void)n_in; (void)out_size; (void)ws_size;
  const int*   ids   = (const int*)d_in[0];
  const float* emb   = (const float*)d_in[1];
  const float* W0    = (const float*)d_in[2];
  // d_in[3] = W_hh0 unused (h_prev = 0)
  const float* bi0   = (const float*)d_in[4];
  const float* bh0   = (const float*)d_in[5];
  const float* W1    = (const float*)d_in[6];
  // d_in[7] = W_hh1 unused
  const float* bi1   = (const float*)d_in[8];
  const float* bh1   = (const float*)d_in[9];
  const float* WL    = (const float*)d_in[10];
  const float* blin  = (const float*)d_in[11];
  float* out = (float*)d_out;

  char* ws = (char*)d_ws;
  const size_t MB = 1024 * 1024;
  _Float16* W0f = (_Float16*)(ws);                  // 2 MB
  _Float16* W1f = (_Float16*)(ws + 2 * MB);         // 2 MB
  _Float16* WLf = (_Float16*)(ws + 4 * MB);         // 0.5 MB
  float*    b0p = (float*)(ws + 4 * MB + 512 * 1024);
  float*    b1p = (float*)(ws + 4 * MB + 512 * 1024 + 8192);
  _Float16* Ef  = (_Float16*)(ws + 8 * MB);         // 51.5 MB (64 MB slot)
  _Float16* H1f = Ef;                               // Ef dead after layer 0
  _Float16* H0f = (_Float16*)(ws + 72 * MB);        // 64 MB
  // total ws use: 136 MB

  prep_kernel<<<13733, 256, 0, stream>>>(emb, W0, bi0, bh0, W1, bi1, bh1, WL,
                                         Ef, W0f, W1f, WLf, b0p, b1p);
  gemm_kernel<0><<<4096, 512, 0, stream>>>(Ef, ids, W0f, b0p, H0f, nullptr, 4, 15);
  gemm_kernel<0><<<4096, 512, 0, stream>>>(H0f, nullptr, W1f, b1p, H1f, nullptr, 4, 15);
  gemm_kernel<1><<<1024, 512, 0, stream>>>(H1f, nullptr, WLf, blin, nullptr, out, 2, 3);
}

// Round 2
// 648.217 us; speedup vs baseline: 1.0841x; 1.0201x over previous
//
#include <hip/hip_runtime.h>
#include <stdint.h>

// LSTM2Encoder: x=emb[ids]; h0=lstm0(x); h1=lstm1(h0); out=relu(h1@Wlin^T+b)
// R4: double-buffered K-loop with 1-iter prefetch + counted vmcnt + raw
// barriers (T3/T4). Wave tile 128x64 (acc 8x4) -> 22.9 KB LDS-read/MFLOP
// (was 30.5). Block 256x128, 4 waves (2x2), 48KB LDS dbuf, ~210 VGPR ->
// 2 blocks/CU so barriers overlap across blocks. XCD-bijective swizzle.
// Epilogue keeps R3's operand-swapped mfma(b,a,acc): acc regs = gates
// i,f,g,o of one unit (gate-inner permuted W'), no shuffles.

typedef _Float16 half8 __attribute__((ext_vector_type(8)));
typedef __attribute__((ext_vector_type(4))) float float4v;
typedef __attribute__((ext_vector_type(4))) unsigned int uint4v;

__device__ __forceinline__ float sigmoidf_(float x) { return 1.0f / (1.0f + __expf(-x)); }
__device__ __forceinline__ float tanhf_(float x) { return 1.0f - 2.0f / (__expf(2.0f * x) + 1.0f); }

__device__ __forceinline__ void gl2lds16(const void* g, void* l) {
  __builtin_amdgcn_global_load_lds(
      (const __attribute__((address_space(1))) void*)g,
      (__attribute__((address_space(3))) void*)l, 16, 0, 0);
}

// ---------------- prep: emb->fp16; weights permuted+cast; biases folded ----
// W'[4j+g][k] = W[g*512+j][k]  (g in {i,f,g,o});  b'[4j+g] = b_ih[n]+b_hh[n]
__global__ __launch_bounds__(256) void prep_kernel(
    const float* __restrict__ emb,
    const float* __restrict__ W0, const float* __restrict__ bi0, const float* __restrict__ bh0,
    const float* __restrict__ W1, const float* __restrict__ bi1, const float* __restrict__ bh1,
    const float* __restrict__ WL,
    _Float16* __restrict__ Ef,
    _Float16* __restrict__ W0f, _Float16* __restrict__ W1f, _Float16* __restrict__ WLf,
    float* __restrict__ b0p, float* __restrict__ b1p)
{
  int id = blockIdx.x * 256 + threadIdx.x;
  if (id < 3216448) {                               // emb cast (50257*512/8)
    const float* s = emb + (size_t)id * 8;
    float4v v0 = *(const float4v*)s;
    float4v v1 = *(const float4v*)(s + 4);
    union { _Float16 h[8]; uint4v u; } P;
#pragma unroll
    for (int e = 0; e < 4; ++e) { P.h[e] = (_Float16)v0[e]; P.h[4 + e] = (_Float16)v1[e]; }
    *(uint4v*)(Ef + (size_t)id * 8) = P.u;
  } else if (id < 3347520) {                        // W0 permute+cast (2048*512/8)
    int u = id - 3216448;
    int np = u >> 6, k0 = (u & 63) << 3;
    int n = ((np & 3) << 9) | (np >> 2);
    const float* s = W0 + n * 512 + k0;
    float4v v0 = *(const float4v*)s;
    float4v v1 = *(const float4v*)(s + 4);
    union { _Float16 h[8]; uint4v u; } P;
#pragma unroll
    for (int e = 0; e < 4; ++e) { P.h[e] = (_Float16)v0[e]; P.h[4 + e] = (_Float16)v1[e]; }
    *(uint4v*)(W0f + np * 512 + k0) = P.u;
  } else if (id < 3478592) {                        // W1
    int u = id - 3347520;
    int np = u >> 6, k0 = (u & 63) << 3;
    int n = ((np & 3) << 9) | (np >> 2);
    const float* s = W1 + n * 512 + k0;
    float4v v0 = *(const float4v*)s;
    float4v v1 = *(const float4v*)(s + 4);
    union { _Float16 h[8]; uint4v u; } P;
#pragma unroll
    for (int e = 0; e < 4; ++e) { P.h[e] = (_Float16)v0[e]; P.h[4 + e] = (_Float16)v1[e]; }
    *(uint4v*)(W1f + np * 512 + k0) = P.u;
  } else if (id < 3511360) {                        // WL straight cast (512*512/8)
    int u = id - 3478592;
    const float* s = WL + (size_t)u * 8;
    float4v v0 = *(const float4v*)s;
    float4v v1 = *(const float4v*)(s + 4);
    union { _Float16 h[8]; uint4v u8; } P;
#pragma unroll
    for (int e = 0; e < 4; ++e) { P.h[e] = (_Float16)v0[e]; P.h[4 + e] = (_Float16)v1[e]; }
    *(uint4v*)(WLf + (size_t)u * 8) = P.u8;
  } else if (id < 3513408) {                        // b0 fold+permute
    int np = id - 3511360;
    int n = ((np & 3) << 9) | (np >> 2);
    b0p[np] = bi0[n] + bh0[n];
  } else if (id < 3515456) {                        // b1
    int np = id - 3513408;
    int n = ((np & 3) << 9) | (np >> 2);
    b1p[np] = bi1[n] + bh1[n];
  }
}

// ---------------- fused fp16 GEMM, 256x128 tile, BK=32, dbuf prefetch ------
// 4 waves as 2x2 grid of 128x64 wave tiles. acc[i][j] = mfma(b[j], a[i], acc)
// -> acc rows = permuted-N (gates), cols = tokens.
// MODE 0: LSTM layer  -> h = sig(o)*tanh(sig(i)*tanh(g)), write h fp16
// MODE 1: final linear -> out = relu(acc + bias), float4 stores
template <int MODE>
__global__ __launch_bounds__(256, 2) void gemm_kernel(
    const _Float16* __restrict__ A, const int* __restrict__ ids,
    const _Float16* __restrict__ B, const float* __restrict__ bias,
    _Float16* __restrict__ Of, float* __restrict__ Out,
    int nbShift, int nbMask)
{
  __shared__ __align__(16) char smem[49152];        // 2 x (16KB A + 8KB B)
  const int T = threadIdx.x;
  const int lane = T & 63;
  const int wv = T >> 6;
  const int wrow = wv >> 1, wcol = wv & 1;          // 2x2 wave grid, 128x64 tiles

  // XCD-bijective swizzle: grid%8==0 for all launches; all nb-blocks of one
  // mb land on one XCD's L2 (A-panel reuse).
  const int nwg = (int)gridDim.x;
  const int bid = (int)blockIdx.x;
  const int swz = (bid & 7) * (nwg >> 3) + (bid >> 3);
  const int mb = swz >> nbShift;
  const int nb = swz & nbMask;
  const size_t t0 = (size_t)mb * 256;
  const int n0 = nb * 128;

  // staging: thread T stages 16B chunk (row r0+seg*64, k-quad qg), qg
  // XOR-swizzled by row pair so frag ds_read_b128 is 2-way (free).
  const int r0 = T >> 2;                            // 0..63
  const int qg = (T & 3) ^ ((r0 >> 1) & 3);
  size_t ra0 = t0 + r0, ra1 = t0 + 64 + r0, ra2 = t0 + 128 + r0, ra3 = t0 + 192 + r0;
  if (ids) {
    ra0 = (size_t)(unsigned)ids[ra0]; ra1 = (size_t)(unsigned)ids[ra1];
    ra2 = (size_t)(unsigned)ids[ra2]; ra3 = (size_t)(unsigned)ids[ra3];
  }
  const _Float16* gA0 = A + ra0 * 512 + qg * 8;
  const _Float16* gA1 = A + ra1 * 512 + qg * 8;
  const _Float16* gA2 = A + ra2 * 512 + qg * 8;
  const _Float16* gA3 = A + ra3 * 512 + qg * 8;
  const _Float16* gB0 = B + (size_t)(n0 + r0) * 512 + qg * 8;
  const _Float16* gB1 = B + (size_t)(n0 + 64 + r0) * 512 + qg * 8;

  // fragment read offsets (iter-invariant); un-swizzle with qs
  const int m_ = lane & 15, qf = lane >> 4;
  const int qs = qf ^ ((m_ >> 1) & 3);
  const int offA = (wrow * 128 + m_) * 32 + qs * 8;
  const int offB = (wcol * 64 + m_) * 32 + qs * 8;

  float4v acc[8][4];
#pragma unroll
  for (int i = 0; i < 8; ++i)
#pragma unroll
    for (int j = 0; j < 4; ++j)
      acc[i][j] = (float4v){0.f, 0.f, 0.f, 0.f};

  _Float16* sA0 = (_Float16*)smem;                  // 256x32
  _Float16* sB0 = (_Float16*)(smem + 16384);        // 128x32
  _Float16* sA1 = (_Float16*)(smem + 24576);
  _Float16* sB1 = (_Float16*)(smem + 40960);

  // prologue: stage K-tile 0 into buffer 0 (6 gl2lds)
  gl2lds16(gA0, sA0 + T * 8);
  gl2lds16(gA1, sA0 + 2048 + T * 8);
  gl2lds16(gA2, sA0 + 4096 + T * 8);
  gl2lds16(gA3, sA0 + 6144 + T * 8);
  gl2lds16(gB0, sB0 + T * 8);
  gl2lds16(gB1, sB0 + 2048 + T * 8);
  gA0 += 32; gA1 += 32; gA2 += 32; gA3 += 32; gB0 += 32; gB1 += 32;

  const _Float16* sAc = sA0;
  const _Float16* sBc = sB0;
  _Float16* sAn = sA1;
  _Float16* sBn = sB1;

#pragma unroll 2
  for (int it = 0; it < 16; ++it) {
    if (it < 15) {                                  // prefetch next K-tile
      gl2lds16(gA0, sAn + T * 8);
      gl2lds16(gA1, sAn + 2048 + T * 8);
      gl2lds16(gA2, sAn + 4096 + T * 8);
      gl2lds16(gA3, sAn + 6144 + T * 8);
      gl2lds16(gB0, sBn + T * 8);
      gl2lds16(gB1, sBn + 2048 + T * 8);
      gA0 += 32; gA1 += 32; gA2 += 32; gA3 += 32; gB0 += 32; gB1 += 32;
      asm volatile("s_waitcnt vmcnt(6)" ::: "memory");  // cur tile landed; next in flight
    } else {
      asm volatile("s_waitcnt vmcnt(0)" ::: "memory");
    }
    __builtin_amdgcn_sched_barrier(0);
    __builtin_amdgcn_s_barrier();                   // all waves' cur stages visible

    half8 a[8], b[4];
#pragma unroll
    for (int i = 0; i < 8; ++i) a[i] = *(const half8*)(sAc + offA + i * 512);
#pragma unroll
    for (int j = 0; j < 4; ++j) b[j] = *(const half8*)(sBc + offB + j * 512);
#pragma unroll
    for (int i = 0; i < 8; ++i)
#pragma unroll
      for (int j = 0; j < 4; ++j)
        acc[i][j] = __builtin_amdgcn_mfma_f32_16x16x32_f16(b[j], a[i], acc[i][j], 0, 0, 0);

    asm volatile("s_waitcnt lgkmcnt(0)" ::: "memory");  // my ds_reads done
    __builtin_amdgcn_sched_barrier(0);
    __builtin_amdgcn_s_barrier();                   // all reads done -> cur overwritable
    const _Float16* tA = sAc; sAc = sAn; sAn = (_Float16*)tA;
    const _Float16* tB = sBc; sBc = sBn; sBn = (_Float16*)tB;
  }

  // bias: acc rows are permuted-N -> 4 consecutive rows per lane = one float4
  float4v bq[4];
#pragma unroll
  for (int j = 0; j < 4; ++j)
    bq[j] = *(const float4v*)(bias + n0 + wcol * 64 + j * 16 + qf * 4);

  if (MODE == 0) {
    _Float16* hT = (_Float16*)smem;                 // 256 x 40 halfs (80B rows)
    const int u0 = wcol * 16 + qf;                  // + j*4 -> unit col 0..31
#pragma unroll
    for (int i = 0; i < 8; ++i) {
      const int trow = wrow * 128 + i * 16 + m_;
#pragma unroll
      for (int j = 0; j < 4; ++j) {
        // regs = gates {i,f,g,o} of unit (u0+j*4); f unused (c_prev=0)
        float yi = acc[i][j][0] + bq[j][0];
        float yg = acc[i][j][2] + bq[j][2];
        float yo = acc[i][j][3] + bq[j][3];
        float cc = sigmoidf_(yi) * tanhf_(yg);
        float hh = sigmoidf_(yo) * tanhf_(cc);
        hT[trow * 40 + u0 + j * 4] = (_Float16)hh;
      }
    }
    __syncthreads();
    // readback: thread T owns token row T (32 units = 64B), 4x16B stores
    const _Float16* src = hT + T * 40;
    uint4v v0 = *(const uint4v*)(src);
    uint4v v1 = *(const uint4v*)(src + 8);
    uint4v v2 = *(const uint4v*)(src + 16);
    uint4v v3 = *(const uint4v*)(src + 24);
    _Float16* dst = Of + (t0 + T) * 512 + (size_t)(nb * 32);
    *(uint4v*)(dst) = v0;
    *(uint4v*)(dst + 8) = v1;
    *(uint4v*)(dst + 16) = v2;
    *(uint4v*)(dst + 24) = v3;
  } else {
#pragma unroll
    for (int i = 0; i < 8; ++i) {
      const size_t row = t0 + wrow * 128 + i * 16 + m_;
#pragma unroll
      for (int j = 0; j < 4; ++j) {
        float4v v;
#pragma unroll
        for (int r = 0; r < 4; ++r)
          v[r] = fmaxf(acc[i][j][r] + bq[j][r], 0.0f);
        *(float4v*)(Out + row * 512 + (size_t)(n0 + wcol * 64 + j * 16 + qf * 4)) = v;
      }
    }
  }
}

extern "C" void kernel_launch(void* const* d_in, const int* in_sizes, int n_in,
                              void* d_out, int out_size, void* d_ws, size_t ws_size,
                              hipStream_t stream) {
  (void)in_sizes; (void)n_in; (void)out_size; (void)ws_size;
  const int*   ids   = (const int*)d_in[0];
  const float* emb   = (const float*)d_in[1];
  const float* W0    = (const float*)d_in[2];
  // d_in[3] = W_hh0 unused (h_prev = 0)
  const float* bi0   = (const float*)d_in[4];
  const float* bh0   = (const float*)d_in[5];
  const float* W1    = (const float*)d_in[6];
  // d_in[7] = W_hh1 unused
  const float* bi1   = (const float*)d_in[8];
  const float* bh1   = (const float*)d_in[9];
  const float* WL    = (const float*)d_in[10];
  const float* blin  = (const float*)d_in[11];
  float* out = (float*)d_out;

  char* ws = (char*)d_ws;
  const size_t MB = 1024 * 1024;
  _Float16* W0f = (_Float16*)(ws);                  // 2 MB
  _Float16* W1f = (_Float16*)(ws + 2 * MB);         // 2 MB
  _Float16* WLf = (_Float16*)(ws + 4 * MB);         // 0.5 MB
  float*    b0p = (float*)(ws + 4 * MB + 512 * 1024);
  float*    b1p = (float*)(ws + 4 * MB + 512 * 1024 + 8192);
  _Float16* Ef  = (_Float16*)(ws + 8 * MB);         // 51.5 MB (64 MB slot)
  _Float16* H1f = Ef;                               // Ef dead after layer 0
  _Float16* H0f = (_Float16*)(ws + 72 * MB);        // 64 MB
  // total ws use: 136 MB

  prep_kernel<<<13733, 256, 0, stream>>>(emb, W0, bi0, bh0, W1, bi1, bh1, WL,
                                         Ef, W0f, W1f, WLf, b0p, b1p);
  gemm_kernel<0><<<4096, 256, 0, stream>>>(Ef, ids, W0f, b0p, H0f, nullptr, 4, 15);
  gemm_kernel<0><<<4096, 256, 0, stream>>>(H0f, nullptr, W1f, b1p, H1f, nullptr, 4, 15);
  gemm_kernel<1><<<1024, 256, 0, stream>>>(H1f, nullptr, WLf, blin, nullptr, out, 2, 3);
}